// Round 1
// baseline (387.688 us; speedup 1.0000x reference)
//
#include <hip/hip_runtime.h>

#define CC   1024
#define C2   2048
#define HH   64
#define WW   64
#define HW   4096
#define MOUT 2048
#define NB   4

typedef short  short8  __attribute__((ext_vector_type(8)));
typedef float  floatx4 __attribute__((ext_vector_type(4)));

static __device__ __forceinline__ unsigned short f2bf(float f) {
  unsigned int u = __builtin_bit_cast(unsigned int, f);
  u = u + 0x7FFFu + ((u >> 16) & 1u);   // RNE truncate to bf16
  return (unsigned short)(u >> 16);
}

// async 16B global -> LDS (DMA: wave-uniform LDS base + lane*16)
static __device__ __forceinline__ void glds16(const unsigned short* g, unsigned short* l) {
  __builtin_amdgcn_global_load_lds(
      (const __attribute__((address_space(1))) void*)g,
      (__attribute__((address_space(3))) void*)l, 16, 0, 0);
}

// ---------------------------------------------------------------------------
// Kernel 1: 3x3 conv (2048 -> 2 ch), SAME pad. R6 structure (unchanged).
// ---------------------------------------------------------------------------
__global__ __launch_bounds__(256)
void conv_off(const float* __restrict__ refer, const float* __restrict__ sup,
              const float* __restrict__ woff, float* __restrict__ off)
{
  const int cz = blockIdx.x;             // channel chunk: 32 channels
  const int ry = blockIdx.y;             // row tile: 8 rows
  const int b  = blockIdx.z;
  const int wv = threadIdx.x >> 6;       // wave 0..3 -> 2 rows each
  const int w  = threadIdx.x & 63;       // column
  const int h0 = ry * 8 + wv * 2;

  const int cc0 = cz * 32;               // global input-channel base
  const float* basep = (cz < 32)
      ? refer + ((size_t)b * CC + cc0) * HW
      : sup   + ((size_t)b * CC + (cc0 - CC)) * HW;

  const int gy0 = h0 - 1;
  const bool top_ok = (gy0 >= 0);
  const bool bot_ok = (h0 + 2 < HH);

  float a00 = 0.f, a01 = 0.f, a10 = 0.f, a11 = 0.f;

  float rn[4];
#pragma unroll
  for (int j = 0; j < 4; j++) {
    const bool ok = (j == 0) ? top_ok : (j == 3) ? bot_ok : true;
    rn[j] = ok ? basep[(gy0 + j) * WW + w] : 0.f;
  }

  for (int ci = 0; ci < 32; ci++) {
    float rc[4];
#pragma unroll
    for (int j = 0; j < 4; j++) rc[j] = rn[j];

    if (ci < 31) {
      const float* pn = basep + (size_t)(ci + 1) * HW;
#pragma unroll
      for (int j = 0; j < 4; j++) {
        const bool ok = (j == 0) ? top_ok : (j == 3) ? bot_ok : true;
        rn[j] = ok ? pn[(gy0 + j) * WW + w] : 0.f;
      }
    }

    float lft[4], rgt[4];
#pragma unroll
    for (int j = 0; j < 4; j++) {
      const float tl = __shfl(rc[j], (w - 1) & 63, 64);
      const float tr = __shfl(rc[j], (w + 1) & 63, 64);
      lft[j] = (w == 0)  ? 0.f : tl;
      rgt[j] = (w == 63) ? 0.f : tr;
    }

    const int cc = cc0 + ci;
    const float* wp0 = woff + (size_t)cc * 9;          // o=0 (dy)
    const float* wp1 = woff + (size_t)(C2 + cc) * 9;   // o=1 (dx)
#pragma unroll
    for (int ky = 0; ky < 3; ky++) {
      const float w00 = wp0[ky * 3 + 0], w01 = wp0[ky * 3 + 1], w02 = wp0[ky * 3 + 2];
      const float w10 = wp1[ky * 3 + 0], w11 = wp1[ky * 3 + 1], w12 = wp1[ky * 3 + 2];
      a00 += lft[ky]     * w00 + rc[ky]     * w01 + rgt[ky]     * w02;
      a01 += lft[ky]     * w10 + rc[ky]     * w11 + rgt[ky]     * w12;
      a10 += lft[ky + 1] * w00 + rc[ky + 1] * w01 + rgt[ky + 1] * w02;
      a11 += lft[ky + 1] * w10 + rc[ky + 1] * w11 + rgt[ky + 1] * w12;
    }
  }

  atomicAdd(&off[((b * 2 + 0) * HH + h0) * WW + w],     a00);
  atomicAdd(&off[((b * 2 + 1) * HH + h0) * WW + w],     a01);
  atomicAdd(&off[((b * 2 + 0) * HH + h0 + 1) * WW + w], a10);
  atomicAdd(&off[((b * 2 + 1) * HH + h0 + 1) * WW + w], a11);
}

// ---------------------------------------------------------------------------
// Kernel 2: fp32 -> bf16 convert for w_def (unchanged)
// ---------------------------------------------------------------------------
__global__ __launch_bounds__(256)
void cvt_bf16(const float* __restrict__ src, unsigned short* __restrict__ dst, int n4)
{
  const int i = blockIdx.x * 256 + threadIdx.x;
  if (i < n4) {
    const float4 f = ((const float4*)src)[i];
    ushort4 u;
    u.x = f2bf(f.x); u.y = f2bf(f.y); u.z = f2bf(f.z); u.w = f2bf(f.w);
    ((ushort4*)dst)[i] = u;
  }
}

// ---------------------------------------------------------------------------
// Kernel 3: bilinear deform-sample (r5 VERIFIED, unchanged).
// ---------------------------------------------------------------------------
__global__ __launch_bounds__(256)
void sample_kern(const float* __restrict__ sup, const float* __restrict__ off,
                 const float* __restrict__ boff, unsigned short* __restrict__ St)
{
  const int h   = blockIdx.x;
  const int ct  = blockIdx.y;
  const int b   = blockIdx.z;
  const int tid = threadIdx.x;

  __shared__ float swy[64], swx[64];
  __shared__ int   sy0[64], sx0[64];
  __shared__ unsigned short tile[64 * 68];

  if (tid < 64) {
    const float dy = off[((b * 2 + 0) * HH + h) * WW + tid] + boff[0];
    const float dx = off[((b * 2 + 1) * HH + h) * WW + tid] + boff[1];
    const float py = dy + (float)h;
    const float px = dx + (float)tid;
    const float y0f = floorf(py), x0f = floorf(px);
    sy0[tid] = (int)y0f;  sx0[tid] = (int)x0f;
    swy[tid] = py - y0f;  swx[tid] = px - x0f;
  }
  __syncthreads();

  const int l   = tid & 63;
  const int cs0 = tid >> 6;
  const int y0 = sy0[l], x0 = sx0[l];
  const int y1 = y0 + 1, x1 = x0 + 1;
  const float wy1 = swy[l], wx1 = swx[l];
  const float wy0 = 1.f - wy1, wx0 = 1.f - wx1;
  const float vy0 = (y0 >= 0 && y0 < HH) ? 1.f : 0.f;
  const float vy1 = (y1 >= 0 && y1 < HH) ? 1.f : 0.f;
  const float vx0 = (x0 >= 0 && x0 < WW) ? 1.f : 0.f;
  const float vx1 = (x1 >= 0 && x1 < WW) ? 1.f : 0.f;
  const int cy0 = min(max(y0, 0), HH - 1), cy1 = min(max(y1, 0), HH - 1);
  const int cx0 = min(max(x0, 0), WW - 1), cx1 = min(max(x1, 0), WW - 1);
  const int i00 = cy0 * WW + cx0, i01 = cy0 * WW + cx1;
  const int i10 = cy1 * WW + cx0, i11 = cy1 * WW + cx1;
  const float w00 = wy0 * wx0 * vy0 * vx0;
  const float w01 = wy0 * wx1 * vy0 * vx1;
  const float w10 = wy1 * wx0 * vy1 * vx0;
  const float w11 = wy1 * wx1 * vy1 * vx1;

  const int cb = ct * 64;
  for (int cs = cs0; cs < 64; cs += 4) {
    const float* sp = sup + ((size_t)b * CC + cb + cs) * HW;
    const float v = w00 * sp[i00] + w01 * sp[i01] + w10 * sp[i10] + w11 * sp[i11];
    tile[cs * 68 + l] = f2bf(v);
  }
  __syncthreads();
  const int cq  = tid & 15;
  const int ls0 = tid >> 4;
  unsigned short* stb = St + ((size_t)b * HW + h * 64) * CC;
  for (int ls = ls0; ls < 64; ls += 16) {
    ushort4 pk;
    pk.x = tile[(cq * 4 + 0) * 68 + ls];
    pk.y = tile[(cq * 4 + 1) * 68 + ls];
    pk.z = tile[(cq * 4 + 2) * 68 + ls];
    pk.w = tile[(cq * 4 + 3) * 68 + ls];
    *(ushort4*)&stb[(size_t)ls * CC + cb + cq * 4] = pk;
  }
}

// ---------------------------------------------------------------------------
// Kernel 4 (NEW, r7): bf16 MFMA GEMM, 256x256 tile, BK=32, 8 waves,
// 3-deep LDS pipeline with counted vmcnt (T3+T4), raw s_barrier phases,
// setprio around MFMA clusters (T5), XOR-swizzled LDS (T2 family).
//
// Race-freedom invariant: iteration t computes from buf[t%3] and stages
// tile t+2 into buf[(t+2)%3] == buf[(t-1)%3]; tile t-1's ds_reads were
// lgkm-waited before iteration t-1's trailing barrier, so the DMA writes
// can never clobber live data. vmcnt(4) at each tile end guarantees tile
// t+1 (issued one iteration ago, older than the 4 in-flight loads of
// tile t+2) has landed before its first ds_read. vmcnt never drains to 0
// in the main loop (only at t==30 tail).
//
// Swizzle (64B rows, 4x16B chunks): LDS(row, c) holds global chunk
// c ^ ((row>>1)&3); staged via pre-swizzled per-lane global source
// (linear DMA dest), read back with the same XOR. Same k-partition into
// 16x16x32 MFMAs as r5 -> bit-identical accumulation order.
// ---------------------------------------------------------------------------
#define STAGE_A(s, kk) do { \
  glds16(gA + (kk),                    &lA[s][(wave * 16) * 32]); \
  glds16(gA + (size_t)128 * CC + (kk), &lA[s][(128 + wave * 16) * 32]); \
} while (0)
#define STAGE_B(s, kk) do { \
  glds16(gB + (kk),                    &lB[s][(wave * 16) * 32]); \
  glds16(gB + (size_t)128 * CC + (kk), &lB[s][(128 + wave * 16) * 32]); \
} while (0)

__global__ __launch_bounds__(512, 2)
void gemm_bt256(const unsigned short* __restrict__ A,
                const unsigned short* __restrict__ Bt,
                float* __restrict__ C)
{
  const int bb = blockIdx.z;
  const int n0 = blockIdx.x * 256;
  const int m0 = blockIdx.y * 256;
  const unsigned short* Bb = Bt + (size_t)bb * HW * CC;
  float* Cb = C + (size_t)bb * (size_t)MOUT * HW;

  __shared__ __align__(16) unsigned short lA[3][256 * 32];   // 48 KB
  __shared__ __align__(16) unsigned short lB[3][256 * 32];   // 48 KB

  const int tid  = threadIdx.x;
  const int wave = tid >> 6;
  const int lane = tid & 63;
  const int wmA  = (wave >> 2) * 128;        // 2 M-warps
  const int wnB  = (wave & 3) * 64;          // 4 N-warps
  const int lrow = lane & 15;
  const int quad = lane >> 4;
  const int rdo  = ((quad ^ ((lrow >> 1) & 3)) << 3);   // swizzled k-chunk (shorts)

  // staging source (pre-swizzled so linear DMA dest lands swizzled content)
  const int srow = tid >> 2;                             // 0..127
  const int schk = (tid & 3) ^ ((tid >> 3) & 3);
  const unsigned short* gA = A  + (size_t)(m0 + srow) * CC + schk * 8;
  const unsigned short* gB = Bb + (size_t)(n0 + srow) * CC + schk * 8;

  // prologue: stage tiles 0 and 1 (8 loads in flight)
  STAGE_A(0, 0);  STAGE_B(0, 0);
  STAGE_A(1, 32); STAGE_B(1, 32);

  floatx4 acc[8][4];
#pragma unroll
  for (int i = 0; i < 8; i++)
#pragma unroll
    for (int j = 0; j < 4; j++)
      acc[i][j] = (floatx4){0.f, 0.f, 0.f, 0.f};

  asm volatile("s_waitcnt vmcnt(4)" ::: "memory");   // tile 0 landed
  __builtin_amdgcn_s_barrier();
  asm volatile("" ::: "memory");

  auto tile_step = [&](int t, int cb, int sb, bool st, int vm) {
    const int k2 = (t + 2) * 32;

    // ---- phase 0: i=0..3 x j=0..3 ----
    short8 af[4], bfr[4];
#pragma unroll
    for (int i = 0; i < 4; i++)
      af[i] = *(const short8*)&lA[cb][(wmA + i * 16 + lrow) * 32 + rdo];
#pragma unroll
    for (int j = 0; j < 4; j++)
      bfr[j] = *(const short8*)&lB[cb][(wnB + j * 16 + lrow) * 32 + rdo];
    if (st) STAGE_A(sb, k2);
    __builtin_amdgcn_s_barrier();
    __builtin_amdgcn_s_setprio(1);
#pragma unroll
    for (int i = 0; i < 4; i++)
#pragma unroll
      for (int j = 0; j < 4; j++)
        acc[i][j] = __builtin_amdgcn_mfma_f32_16x16x32_bf16(af[i], bfr[j], acc[i][j], 0, 0, 0);
    __builtin_amdgcn_s_setprio(0);
    __builtin_amdgcn_s_barrier();

    // ---- phase 1: i=4..7 x j=0..3 (bfr still live) ----
    short8 ag[4];
#pragma unroll
    for (int i = 0; i < 4; i++)
      ag[i] = *(const short8*)&lA[cb][(wmA + 64 + i * 16 + lrow) * 32 + rdo];
    if (st) STAGE_B(sb, k2);
    __builtin_amdgcn_s_barrier();
    __builtin_amdgcn_s_setprio(1);
#pragma unroll
    for (int i = 0; i < 4; i++)
#pragma unroll
      for (int j = 0; j < 4; j++)
        acc[4 + i][j] = __builtin_amdgcn_mfma_f32_16x16x32_bf16(ag[i], bfr[j], acc[4 + i][j], 0, 0, 0);
    __builtin_amdgcn_s_setprio(0);
    // tile boundary: counted wait (tile t+1 landed; tile t+2's 4 may fly)
    if (vm == 4)      asm volatile("s_waitcnt vmcnt(4)" ::: "memory");
    else if (vm == 0) asm volatile("s_waitcnt vmcnt(0)" ::: "memory");
    __builtin_amdgcn_s_barrier();
    asm volatile("" ::: "memory");
  };

#pragma unroll 1
  for (int tt = 0; tt < 30; tt += 3) {
    tile_step(tt + 0, 0, 2, true, 4);
    tile_step(tt + 1, 1, 0, true, 4);
    tile_step(tt + 2, 2, 1, true, 4);
  }
  tile_step(30, 0, 2, false, 0);    // drain: tile 31 landed
  tile_step(31, 1, 0, false, -1);

  // epilogue: C[m][n]
#pragma unroll
  for (int i = 0; i < 8; i++) {
    const int mbase = m0 + wmA + i * 16 + quad * 4;
#pragma unroll
    for (int j = 0; j < 4; j++) {
      const int n = n0 + wnB + j * 16 + lrow;
      float* cp = Cb + (size_t)mbase * HW + n;
#pragma unroll
      for (int r = 0; r < 4; r++)
        cp[(size_t)r * HW] = acc[i][j][r];
    }
  }
}

// ---------------------------------------------------------------------------
extern "C" void kernel_launch(void* const* d_in, const int* in_sizes, int n_in,
                              void* d_out, int out_size, void* d_ws, size_t ws_size,
                              hipStream_t stream)
{
  const float* refer = (const float*)d_in[0];
  const float* sup   = (const float*)d_in[1];
  const float* woff  = (const float*)d_in[2];
  const float* boff  = (const float*)d_in[3];
  const float* wdef  = (const float*)d_in[4];
  float* out = (float*)d_out;

  // workspace: [offsets 512KB][w_def bf16 4MB][S_t bf16 32MB]
  char* ws = (char*)d_ws;
  float* off            = (float*)ws;
  unsigned short* wdefb = (unsigned short*)(ws + (512u << 10));
  unsigned short* St    = (unsigned short*)(ws + (512u << 10) + (4u << 20));

  hipMemsetAsync(off, 0, (size_t)NB * 2 * HW * sizeof(float), stream);
  conv_off<<<dim3(64, 8, NB), 256, 0, stream>>>(refer, sup, woff, off);
  cvt_bf16<<<dim3((MOUT * CC / 4 + 255) / 256), 256, 0, stream>>>(wdef, wdefb, MOUT * CC / 4);
  sample_kern<<<dim3(HH, 16, NB), 256, 0, stream>>>(sup, off, boff, St);
  gemm_bt256<<<dim3(HW / 256, MOUT / 256, NB), 512, 0, stream>>>(wdefb, St, out);
}